// Round 1
// baseline (1834.946 us; speedup 1.0000x reference)
//
#include <hip/hip_runtime.h>
#include <hip/hip_bf16.h>

// ---------------------------------------------------------------------------
// RevGAT forward on MI355X.
// Pipeline per call (deterministic, all on `stream`):
//   degrees -> CSR(dst) -> bf16 weight/x conversion ->
//   [GATconv x5 with bf16 MFMA GEMMs + fused edge-softmax aggregation]
//   with BN(+relu)->bf16 between layers.
// ---------------------------------------------------------------------------

#define IN_F   256
#define HIDW   256          // HEADS*HID
#define CLS    40

typedef __attribute__((ext_vector_type(8))) __bf16 bf16x8;
typedef __attribute__((ext_vector_type(4))) float  f32x4;

__device__ inline bf16x8 zb8() {
    bf16x8 v;
#pragma unroll
    for (int i = 0; i < 8; ++i) v[i] = (__bf16)0.f;
    return v;
}
__device__ inline bf16x8 ldb8(const __hip_bfloat16* p) {
    return *reinterpret_cast<const bf16x8*>(p);
}

// ------------------------------ graph prep --------------------------------
__global__ void k_hist(const int* __restrict__ src, const int* __restrict__ dst,
                       int E, int* __restrict__ outdeg, int* __restrict__ indeg) {
    for (int e = blockIdx.x * blockDim.x + threadIdx.x; e < E; e += gridDim.x * blockDim.x) {
        atomicAdd(&outdeg[src[e]], 1);
        atomicAdd(&indeg[dst[e]], 1);
    }
}

__global__ void k_scan1(const int* __restrict__ cnt, int N, int* __restrict__ rp1,
                        int* __restrict__ bsum) {
    __shared__ int sm[256];
    int i = blockIdx.x * 256 + threadIdx.x;
    int v = (i < N) ? cnt[i] : 0;
    sm[threadIdx.x] = v;
    __syncthreads();
    for (int off = 1; off < 256; off <<= 1) {
        int t = (threadIdx.x >= off) ? sm[threadIdx.x - off] : 0;
        __syncthreads();
        sm[threadIdx.x] += t;
        __syncthreads();
    }
    if (i < N) rp1[i] = sm[threadIdx.x];                  // inclusive within block
    if (threadIdx.x == 255) bsum[blockIdx.x] = sm[255];
}

__global__ void k_scan2(int* __restrict__ bsum, int nb) {
    __shared__ int sm[256];
    int v = (threadIdx.x < nb) ? bsum[threadIdx.x] : 0;
    sm[threadIdx.x] = v;
    __syncthreads();
    for (int off = 1; off < 256; off <<= 1) {
        int t = (threadIdx.x >= off) ? sm[threadIdx.x - off] : 0;
        __syncthreads();
        sm[threadIdx.x] += t;
        __syncthreads();
    }
    if (threadIdx.x < nb) bsum[threadIdx.x] = sm[threadIdx.x] - v;   // exclusive
}

__global__ void k_scan3(int* __restrict__ rp1, const int* __restrict__ bsumExcl, int N) {
    int i = blockIdx.x * 256 + threadIdx.x;
    if (i < N) rp1[i] += bsumExcl[blockIdx.x];
    if (blockIdx.x == 0 && threadIdx.x == 0) rp1[-1] = 0;            // row_ptr[0] = 0
}

__global__ void k_scatter(const int* __restrict__ src, const int* __restrict__ dst,
                          int E, int* __restrict__ cursor, int* __restrict__ csr_src) {
    for (int e = blockIdx.x * blockDim.x + threadIdx.x; e < E; e += gridDim.x * blockDim.x) {
        int d = dst[e];
        int pos = atomicAdd(&cursor[d], 1);
        csr_src[pos] = src[e];
    }
}

__global__ void k_deg(const int* __restrict__ outdeg, const int* __restrict__ indeg,
                      float* __restrict__ oi, float* __restrict__ insq, int N) {
    int i = blockIdx.x * 256 + threadIdx.x;
    if (i < N) {
        int od = outdeg[i]; if (od < 1) od = 1;
        int id = indeg[i];  if (id < 1) id = 1;
        oi[i]   = rsqrtf((float)od);
        insq[i] = sqrtf((float)id);
    }
}

// --------------------------- dtype conversion -----------------------------
__global__ void k_cvt(const float* __restrict__ s, __hip_bfloat16* __restrict__ d, int n) {
    for (int i = blockIdx.x * blockDim.x + threadIdx.x; i < n; i += gridDim.x * blockDim.x)
        d[i] = __float2bfloat16(s[i]);
}

__global__ void k_cvt6(const float* s0, __hip_bfloat16* d0, int n0,
                       const float* s1, __hip_bfloat16* d1, int n1,
                       const float* s2, __hip_bfloat16* d2, int n2,
                       const float* s3, __hip_bfloat16* d3, int n3,
                       const float* s4, __hip_bfloat16* d4, int n4,
                       const float* s5, __hip_bfloat16* d5, int n5) {
    const float* ss; __hip_bfloat16* dd; int nn;
    switch (blockIdx.y) {
        case 0: ss = s0; dd = d0; nn = n0; break;
        case 1: ss = s1; dd = d1; nn = n1; break;
        case 2: ss = s2; dd = d2; nn = n2; break;
        case 3: ss = s3; dd = d3; nn = n3; break;
        case 4: ss = s4; dd = d4; nn = n4; break;
        default: ss = s5; dd = d5; nn = n5; break;
    }
    for (int i = blockIdx.x * blockDim.x + threadIdx.x; i < nn; i += gridDim.x * blockDim.x)
        dd[i] = __float2bfloat16(ss[i]);
}

// ------------------------------ bf16 GEMM ---------------------------------
// C[M,NOUT] = A[M,K] @ B[NOUT,K]^T  (+ base) (+ bias), A/B bf16, acc f32.
// 256 thr = 4 waves; wave does 32 rows x NOUT cols via 16x16x32 MFMA.
template<int K, int NOUT, bool OUTBF>
__global__ __launch_bounds__(256) void k_gemm_bt(
    const __hip_bfloat16* __restrict__ A,
    const __hip_bfloat16* __restrict__ B,
    void* __restrict__ C, int M, int ldc,
    const float* __restrict__ base, int ldbase,
    const float* __restrict__ bias) {
    constexpr int KF  = K / 32;
    constexpr int NCT = (NOUT + 15) / 16;
    const int wave = threadIdx.x >> 6, lane = threadIdx.x & 63;
    const int row0 = blockIdx.x * 128 + wave * 32;
    const int rf = lane & 15, kg = lane >> 4;

    bf16x8 a[2][KF];
#pragma unroll
    for (int rt = 0; rt < 2; ++rt) {
        int row = row0 + rt * 16 + rf;
        const __hip_bfloat16* ap = A + (size_t)row * K + kg * 8;
#pragma unroll
        for (int kf = 0; kf < KF; ++kf)
            a[rt][kf] = (row < M) ? ldb8(ap + kf * 32) : zb8();
    }

    for (int ct = 0; ct < NCT; ++ct) {
        int col = ct * 16 + rf;
        bf16x8 b[KF];
        const __hip_bfloat16* bp = B + (size_t)col * K + kg * 8;
#pragma unroll
        for (int kf = 0; kf < KF; ++kf)
            b[kf] = (col < NOUT) ? ldb8(bp + kf * 32) : zb8();
        f32x4 acc0 = {0.f, 0.f, 0.f, 0.f};
        f32x4 acc1 = {0.f, 0.f, 0.f, 0.f};
#pragma unroll
        for (int kf = 0; kf < KF; ++kf) {
            acc0 = __builtin_amdgcn_mfma_f32_16x16x32_bf16(a[0][kf], b[kf], acc0, 0, 0, 0);
            acc1 = __builtin_amdgcn_mfma_f32_16x16x32_bf16(a[1][kf], b[kf], acc1, 0, 0, 0);
        }
        // D: col = lane&15, row = 4*(lane>>4)+r   [m89-verified]
        int ccol = ct * 16 + rf;
        if (ccol < NOUT) {
#pragma unroll
            for (int rt = 0; rt < 2; ++rt) {
                f32x4 acc = rt ? acc1 : acc0;
#pragma unroll
                for (int r = 0; r < 4; ++r) {
                    int row = row0 + rt * 16 + kg * 4 + r;
                    if (row < M) {
                        float v = acc[r];
                        if (base) v += base[(size_t)row * ldbase + ccol];
                        if (bias) v += bias[ccol];
                        if (OUTBF)
                            ((__hip_bfloat16*)C)[(size_t)row * ldc + ccol] = __float2bfloat16(v);
                        else
                            ((float*)C)[(size_t)row * ldc + ccol] = v;
                    }
                }
            }
        }
    }
}

// --------------------------- attention el / er ----------------------------
// el[n,h] = oi[n] * sum_d ft0[n,h,d]*attn_l[h,d] ; er[n,h] = sum_d ft0*attn_r
template<int H, int D>
__global__ __launch_bounds__(256) void k_eler(
    const __hip_bfloat16* __restrict__ ftb,
    const float* __restrict__ attn_l, const float* __restrict__ attn_r,
    const float* __restrict__ oi,
    float* __restrict__ el, float* __restrict__ er, int N) {
    constexpr int W = H * D;
    const int lane = threadIdx.x & 63;
    const int n = blockIdx.x * 4 + (threadIdx.x >> 6);
    if (n >= N) return;
    float pl[H], pr[H];
#pragma unroll
    for (int h = 0; h < H; ++h) { pl[h] = 0.f; pr[h] = 0.f; }
    for (int idx = lane; idx < W; idx += 64) {
        float f = __bfloat162float(ftb[(size_t)n * W + idx]);
        int h = idx / D;
        pl[h] += f * attn_l[idx];
        pr[h] += f * attn_r[idx];
    }
#pragma unroll
    for (int off = 32; off; off >>= 1)
#pragma unroll
        for (int h = 0; h < H; ++h) {
            pl[h] += __shfl_xor(pl[h], off);
            pr[h] += __shfl_xor(pr[h], off);
        }
    if (lane == 0) {
        float o = oi[n];
#pragma unroll
        for (int h = 0; h < H; ++h) {
            el[(size_t)n * H + h] = o * pl[h];
            er[(size_t)n * H + h] = pr[h];
        }
    }
}

// ------------- fused edge softmax + message aggregation (per dst) ---------
// out[v,:] += in_sqrt[v] * (sum_e exp(s_e - max) * oi[u] * ft0[u,:]) / denom
template<int H, int D>
__global__ __launch_bounds__(256) void k_agg(
    const __hip_bfloat16* __restrict__ ftb,
    const float* __restrict__ el, const float* __restrict__ er,
    const int* __restrict__ row_ptr, const int* __restrict__ csr_src,
    const float* __restrict__ oi, const float* __restrict__ insq,
    float* __restrict__ out, int ldc, int N) {
    constexpr int W = H * D;
    constexpr int J = (W + 63) / 64;
    const int lane = threadIdx.x & 63;
    const int v = blockIdx.x * 4 + (threadIdx.x >> 6);
    if (v >= N) return;
    const int s = row_ptr[v], e = row_ptr[v + 1];
    float erv[H], mh[H];
#pragma unroll
    for (int h = 0; h < H; ++h) { erv[h] = er[(size_t)v * H + h]; mh[h] = -3.0e38f; }
    for (int p = s; p < e; ++p) {
        int u = csr_src[p];
#pragma unroll
        for (int h = 0; h < H; ++h) {
            float sc = el[(size_t)u * H + h] + erv[h];
            sc = sc >= 0.f ? sc : 0.2f * sc;
            mh[h] = fmaxf(mh[h], sc);
        }
    }
    float denom[H], acc[J];
#pragma unroll
    for (int h = 0; h < H; ++h) denom[h] = 0.f;
#pragma unroll
    for (int j = 0; j < J; ++j) acc[j] = 0.f;
    for (int p = s; p < e; ++p) {
        int u = csr_src[p];
        float ou = oi[u];
        float wo[H];
#pragma unroll
        for (int h = 0; h < H; ++h) {
            float sc = el[(size_t)u * H + h] + erv[h];
            sc = sc >= 0.f ? sc : 0.2f * sc;
            float w = __expf(sc - mh[h]);
            denom[h] += w;
            wo[h] = w * ou;
        }
#pragma unroll
        for (int j = 0; j < J; ++j) {
            int idx = lane + j * 64;
            if (idx < W) {
                int h = idx / D;
                acc[j] += wo[h] * __bfloat162float(ftb[(size_t)u * W + idx]);
            }
        }
    }
    float iv = insq[v];
#pragma unroll
    for (int j = 0; j < J; ++j) {
        int idx = lane + j * 64;
        if (idx < W) {
            int h = idx / D;
            out[(size_t)v * ldc + idx] += iv * acc[j] / fmaxf(denom[h], 1e-9f);
        }
    }
}

// ------------------------------ batch norm --------------------------------
template<int F>
__global__ __launch_bounds__(256) void k_bn_part(const float* __restrict__ in, int ldin, int N,
                                                 float* __restrict__ psum, float* __restrict__ psum2) {
    constexpr int SL = 256 / F;              // 1 (F=256) or 2 (F=128)
    const int col = threadIdx.x % F;
    const int pr = blockIdx.x * SL + threadIdx.x / F;
    const int PRT = gridDim.x * SL;
    float s = 0.f, s2 = 0.f;
    for (int r = pr; r < N; r += PRT) {
        float v = in[(size_t)r * ldin + col];
        s += v; s2 += v * v;
    }
    psum[pr * F + col] = s;
    psum2[pr * F + col] = s2;
}

template<int F>
__global__ __launch_bounds__(256) void k_bn_fin(const float* __restrict__ psum,
                                                const float* __restrict__ psum2, int PRT,
                                                const float* __restrict__ gamma,
                                                const float* __restrict__ beta,
                                                float* __restrict__ scale,
                                                float* __restrict__ shift, int N) {
    int col = threadIdx.x;
    if (col >= F) return;
    float s = 0.f, s2 = 0.f;
    for (int pr = 0; pr < PRT; ++pr) { s += psum[pr * F + col]; s2 += psum2[pr * F + col]; }
    float mu = s / N;
    float var = s2 / N - mu * mu;
    float isd = rsqrtf(var + 1e-5f);
    float g = gamma[col];
    scale[col] = g * isd;
    shift[col] = beta[col] - g * isd * mu;
}

template<int F>
__global__ __launch_bounds__(256) void k_bn_apply(const float* __restrict__ in, int ldin, int N,
                                                  const float* __restrict__ scale,
                                                  const float* __restrict__ shift,
                                                  __hip_bfloat16* __restrict__ outbf) {
    int total = N * F;
    for (int idx = blockIdx.x * blockDim.x + threadIdx.x; idx < total;
         idx += gridDim.x * blockDim.x) {
        int r = idx / F, c = idx % F;
        float v = in[(size_t)r * ldin + c] * scale[c] + shift[c];
        outbf[idx] = __float2bfloat16(fmaxf(v, 0.f));
    }
}

// ------------------------------- launcher ---------------------------------
extern "C" void kernel_launch(void* const* d_in, const int* in_sizes, int n_in,
                              void* d_out, int out_size, void* d_ws, size_t ws_size,
                              hipStream_t stream) {
    const float* x           = (const float*)d_in[0];
    const int*   src         = (const int*)d_in[1];
    const int*   dst         = (const int*)d_in[2];
    const float* W0          = (const float*)d_in[3];
    const float* attn_l0     = (const float*)d_in[4];
    const float* attn_r0     = (const float*)d_in[5];
    const float* resW0       = (const float*)d_in[6];
    const float* mid_bn_g    = (const float*)d_in[7];
    const float* mid_bn_b    = (const float*)d_in[8];
    const float* mid_W       = (const float*)d_in[9];
    const float* mid_attn_l  = (const float*)d_in[10];
    const float* mid_attn_r  = (const float*)d_in[11];
    const float* mid_resW    = (const float*)d_in[12];
    const float* norm_gamma  = (const float*)d_in[13];
    const float* norm_beta   = (const float*)d_in[14];
    const float* W_last      = (const float*)d_in[15];
    const float* attn_l_last = (const float*)d_in[16];
    const float* attn_r_last = (const float*)d_in[17];
    const float* resW_last   = (const float*)d_in[18];
    const float* bias_last   = (const float*)d_in[19];

    const int N = in_sizes[0] / IN_F;
    const int E = in_sizes[1];

    // ---- workspace carve-up (256B aligned) ----
    char* p = (char*)d_ws;
    size_t used = 0;
    auto take = [&](size_t bytes) -> char* {
        char* r = p;
        size_t adv = (bytes + 255) & ~(size_t)255;
        p += adv; used += adv;
        return r;
    };
    float*          h       = (float*)take((size_t)N * HIDW * 4);
    __hip_bfloat16* xbf     = (__hip_bfloat16*)take((size_t)N * HIDW * 2);
    __hip_bfloat16* ftb     = (__hip_bfloat16*)take((size_t)N * HIDW * 2);
    float*          el      = (float*)take((size_t)N * 4 * 4);
    float*          er      = (float*)take((size_t)N * 4 * 4);
    float*          oi      = (float*)take((size_t)N * 4);
    float*          insq    = (float*)take((size_t)N * 4);
    int*            indeg   = (int*)take((size_t)N * 4);
    int*            outdeg  = (int*)take((size_t)N * 4);
    int*            row_ptr = (int*)take((size_t)(N + 1) * 4);
    int*            cursor  = (int*)take((size_t)N * 4);
    int*            csr_src = (int*)take((size_t)E * 4);
    int*            bsum    = (int*)take(256 * 4);
    float*          psum    = (float*)take(65536);
    float*          psum2   = (float*)take(65536);
    float*          scale   = (float*)take(1024);
    float*          shift   = (float*)take(1024);
    __hip_bfloat16* W0bf      = (__hip_bfloat16*)take(65536 * 2);
    __hip_bfloat16* resW0bf   = (__hip_bfloat16*)take(65536 * 2);
    __hip_bfloat16* midWbf    = (__hip_bfloat16*)take(65536 * 2);
    __hip_bfloat16* midresWbf = (__hip_bfloat16*)take(65536 * 2);
    __hip_bfloat16* Wlastbf   = (__hip_bfloat16*)take(10240 * 2);
    __hip_bfloat16* resWlastbf= (__hip_bfloat16*)take(10240 * 2);
    if (used > ws_size) return;   // out of workspace: leave output poisoned (visible failure)

    const int nbN = (N + 255) / 256;
    const int NB4 = (N + 3) / 4;
    const int GW  = (N + 127) / 128;

    // ---- graph prep ----
    hipMemsetAsync(indeg, 0, (size_t)N * 4, stream);
    hipMemsetAsync(outdeg, 0, (size_t)N * 4, stream);
    k_hist<<<1024, 256, 0, stream>>>(src, dst, E, outdeg, indeg);
    k_scan1<<<nbN, 256, 0, stream>>>(indeg, N, row_ptr + 1, bsum);
    k_scan2<<<1, 256, 0, stream>>>(bsum, nbN);
    k_scan3<<<nbN, 256, 0, stream>>>(row_ptr + 1, bsum, N);
    hipMemcpyAsync(cursor, row_ptr, (size_t)N * 4, hipMemcpyDeviceToDevice, stream);
    k_scatter<<<1024, 256, 0, stream>>>(src, dst, E, cursor, csr_src);
    k_deg<<<nbN, 256, 0, stream>>>(outdeg, indeg, oi, insq, N);

    // ---- weight + input conversion ----
    k_cvt6<<<dim3(64, 6), 256, 0, stream>>>(W0, W0bf, 65536,
                                            resW0, resW0bf, 65536,
                                            mid_W, midWbf, 65536,
                                            mid_resW, midresWbf, 65536,
                                            W_last, Wlastbf, 10240,
                                            resW_last, resWlastbf, 10240);
    k_cvt<<<2048, 256, 0, stream>>>(x, xbf, N * IN_F);

    // ---- layer 0: GATConv(256 -> 4x64) ----
    k_gemm_bt<256, 256, true><<<GW, 256, 0, stream>>>(xbf, W0bf, ftb, N, 256, nullptr, 0, nullptr);
    k_eler<4, 64><<<NB4, 256, 0, stream>>>(ftb, attn_l0, attn_r0, oi, el, er, N);
    k_gemm_bt<256, 256, false><<<GW, 256, 0, stream>>>(xbf, resW0bf, h, N, 256, nullptr, 0, nullptr);
    k_agg<4, 64><<<NB4, 256, 0, stream>>>(ftb, el, er, row_ptr, csr_src, oi, insq, h, 256, N);

    // ---- reversible middle layers ----
    for (int l = 0; l < 2; ++l) {
        for (int g = 0; g < 2; ++g) {
            const int inoff  = (g == 0) ? 128 : 0;
            const int outoff = (g == 0) ? 0 : 128;
            const int pg = l * 2 + g;
            k_bn_part<128><<<64, 256, 0, stream>>>(h + inoff, 256, N, psum, psum2);
            k_bn_fin<128><<<1, 256, 0, stream>>>(psum, psum2, 128,
                                                 mid_bn_g + pg * 128, mid_bn_b + pg * 128,
                                                 scale, shift, N);
            k_bn_apply<128><<<2048, 256, 0, stream>>>(h + inoff, 256, N, scale, shift, xbf);
            k_gemm_bt<128, 128, true><<<GW, 256, 0, stream>>>(xbf, midWbf + pg * 16384, ftb,
                                                              N, 128, nullptr, 0, nullptr);
            k_eler<4, 32><<<NB4, 256, 0, stream>>>(ftb, mid_attn_l + pg * 128,
                                                   mid_attn_r + pg * 128, oi, el, er, N);
            k_gemm_bt<128, 128, false><<<GW, 256, 0, stream>>>(xbf, midresWbf + pg * 16384,
                                                               h + outoff, N, 256,
                                                               h + outoff, 256, nullptr);
            k_agg<4, 32><<<NB4, 256, 0, stream>>>(ftb, el, er, row_ptr, csr_src, oi, insq,
                                                  h + outoff, 256, N);
        }
    }

    // ---- final norm + GATConv(256 -> 1x40) + bias ----
    k_bn_part<256><<<64, 256, 0, stream>>>(h, 256, N, psum, psum2);
    k_bn_fin<256><<<1, 256, 0, stream>>>(psum, psum2, 64, norm_gamma, norm_beta, scale, shift, N);
    k_bn_apply<256><<<2048, 256, 0, stream>>>(h, 256, N, scale, shift, xbf);
    k_gemm_bt<256, 40, true><<<GW, 256, 0, stream>>>(xbf, Wlastbf, ftb, N, 40, nullptr, 0, nullptr);
    k_eler<1, 40><<<NB4, 256, 0, stream>>>(ftb, attn_l_last, attn_r_last, oi, el, er, N);
    k_gemm_bt<256, 40, false><<<GW, 256, 0, stream>>>(xbf, resWlastbf, (float*)d_out, N, 40,
                                                      nullptr, 0, bias_last);
    k_agg<1, 40><<<NB4, 256, 0, stream>>>(ftb, el, er, row_ptr, csr_src, oi, insq,
                                          (float*)d_out, 40, N);
}

// Round 2
// 1202.038 us; speedup vs baseline: 1.5265x; 1.5265x over previous
//
#include <hip/hip_runtime.h>
#include <hip/hip_bf16.h>

// ---------------------------------------------------------------------------
// RevGAT forward on MI355X.
// Pipeline per call (deterministic, all on `stream`):
//   degrees -> CSR(dst) -> bf16 weight/x conversion ->
//   [GATconv x5 with bf16 MFMA GEMMs + fused edge-softmax aggregation]
//   with BN(+relu)->bf16 between layers.
// R2: BN stats widened to 1024 blocks + per-column finalize (was 950us @2.7% occ).
// ---------------------------------------------------------------------------

#define IN_F   256
#define HIDW   256          // HEADS*HID
#define CLS    40

typedef __attribute__((ext_vector_type(8))) __bf16 bf16x8;
typedef __attribute__((ext_vector_type(4))) float  f32x4;

__device__ inline bf16x8 zb8() {
    bf16x8 v;
#pragma unroll
    for (int i = 0; i < 8; ++i) v[i] = (__bf16)0.f;
    return v;
}
__device__ inline bf16x8 ldb8(const __hip_bfloat16* p) {
    return *reinterpret_cast<const bf16x8*>(p);
}

// ------------------------------ graph prep --------------------------------
__global__ void k_hist(const int* __restrict__ src, const int* __restrict__ dst,
                       int E, int* __restrict__ outdeg, int* __restrict__ indeg) {
    for (int e = blockIdx.x * blockDim.x + threadIdx.x; e < E; e += gridDim.x * blockDim.x) {
        atomicAdd(&outdeg[src[e]], 1);
        atomicAdd(&indeg[dst[e]], 1);
    }
}

__global__ void k_scan1(const int* __restrict__ cnt, int N, int* __restrict__ rp1,
                        int* __restrict__ bsum) {
    __shared__ int sm[256];
    int i = blockIdx.x * 256 + threadIdx.x;
    int v = (i < N) ? cnt[i] : 0;
    sm[threadIdx.x] = v;
    __syncthreads();
    for (int off = 1; off < 256; off <<= 1) {
        int t = (threadIdx.x >= off) ? sm[threadIdx.x - off] : 0;
        __syncthreads();
        sm[threadIdx.x] += t;
        __syncthreads();
    }
    if (i < N) rp1[i] = sm[threadIdx.x];                  // inclusive within block
    if (threadIdx.x == 255) bsum[blockIdx.x] = sm[255];
}

__global__ void k_scan2(int* __restrict__ bsum, int nb) {
    __shared__ int sm[256];
    int v = (threadIdx.x < nb) ? bsum[threadIdx.x] : 0;
    sm[threadIdx.x] = v;
    __syncthreads();
    for (int off = 1; off < 256; off <<= 1) {
        int t = (threadIdx.x >= off) ? sm[threadIdx.x - off] : 0;
        __syncthreads();
        sm[threadIdx.x] += t;
        __syncthreads();
    }
    if (threadIdx.x < nb) bsum[threadIdx.x] = sm[threadIdx.x] - v;   // exclusive
}

__global__ void k_scan3(int* __restrict__ rp1, const int* __restrict__ bsumExcl, int N) {
    int i = blockIdx.x * 256 + threadIdx.x;
    if (i < N) rp1[i] += bsumExcl[blockIdx.x];
    if (blockIdx.x == 0 && threadIdx.x == 0) rp1[-1] = 0;            // row_ptr[0] = 0
}

__global__ void k_scatter(const int* __restrict__ src, const int* __restrict__ dst,
                          int E, int* __restrict__ cursor, int* __restrict__ csr_src) {
    for (int e = blockIdx.x * blockDim.x + threadIdx.x; e < E; e += gridDim.x * blockDim.x) {
        int d = dst[e];
        int pos = atomicAdd(&cursor[d], 1);
        csr_src[pos] = src[e];
    }
}

__global__ void k_deg(const int* __restrict__ outdeg, const int* __restrict__ indeg,
                      float* __restrict__ oi, float* __restrict__ insq, int N) {
    int i = blockIdx.x * 256 + threadIdx.x;
    if (i < N) {
        int od = outdeg[i]; if (od < 1) od = 1;
        int id = indeg[i];  if (id < 1) id = 1;
        oi[i]   = rsqrtf((float)od);
        insq[i] = sqrtf((float)id);
    }
}

// --------------------------- dtype conversion -----------------------------
__global__ void k_cvt(const float* __restrict__ s, __hip_bfloat16* __restrict__ d, int n) {
    for (int i = blockIdx.x * blockDim.x + threadIdx.x; i < n; i += gridDim.x * blockDim.x)
        d[i] = __float2bfloat16(s[i]);
}

__global__ void k_cvt6(const float* s0, __hip_bfloat16* d0, int n0,
                       const float* s1, __hip_bfloat16* d1, int n1,
                       const float* s2, __hip_bfloat16* d2, int n2,
                       const float* s3, __hip_bfloat16* d3, int n3,
                       const float* s4, __hip_bfloat16* d4, int n4,
                       const float* s5, __hip_bfloat16* d5, int n5) {
    const float* ss; __hip_bfloat16* dd; int nn;
    switch (blockIdx.y) {
        case 0: ss = s0; dd = d0; nn = n0; break;
        case 1: ss = s1; dd = d1; nn = n1; break;
        case 2: ss = s2; dd = d2; nn = n2; break;
        case 3: ss = s3; dd = d3; nn = n3; break;
        case 4: ss = s4; dd = d4; nn = n4; break;
        default: ss = s5; dd = d5; nn = n5; break;
    }
    for (int i = blockIdx.x * blockDim.x + threadIdx.x; i < nn; i += gridDim.x * blockDim.x)
        dd[i] = __float2bfloat16(ss[i]);
}

// ------------------------------ bf16 GEMM ---------------------------------
// C[M,NOUT] = A[M,K] @ B[NOUT,K]^T  (+ base) (+ bias), A/B bf16, acc f32.
// 256 thr = 4 waves; wave does 32 rows x NOUT cols via 16x16x32 MFMA.
template<int K, int NOUT, bool OUTBF>
__global__ __launch_bounds__(256) void k_gemm_bt(
    const __hip_bfloat16* __restrict__ A,
    const __hip_bfloat16* __restrict__ B,
    void* __restrict__ C, int M, int ldc,
    const float* __restrict__ base, int ldbase,
    const float* __restrict__ bias) {
    constexpr int KF  = K / 32;
    constexpr int NCT = (NOUT + 15) / 16;
    const int wave = threadIdx.x >> 6, lane = threadIdx.x & 63;
    const int row0 = blockIdx.x * 128 + wave * 32;
    const int rf = lane & 15, kg = lane >> 4;

    bf16x8 a[2][KF];
#pragma unroll
    for (int rt = 0; rt < 2; ++rt) {
        int row = row0 + rt * 16 + rf;
        const __hip_bfloat16* ap = A + (size_t)row * K + kg * 8;
#pragma unroll
        for (int kf = 0; kf < KF; ++kf)
            a[rt][kf] = (row < M) ? ldb8(ap + kf * 32) : zb8();
    }

    for (int ct = 0; ct < NCT; ++ct) {
        int col = ct * 16 + rf;
        bf16x8 b[KF];
        const __hip_bfloat16* bp = B + (size_t)col * K + kg * 8;
#pragma unroll
        for (int kf = 0; kf < KF; ++kf)
            b[kf] = (col < NOUT) ? ldb8(bp + kf * 32) : zb8();
        f32x4 acc0 = {0.f, 0.f, 0.f, 0.f};
        f32x4 acc1 = {0.f, 0.f, 0.f, 0.f};
#pragma unroll
        for (int kf = 0; kf < KF; ++kf) {
            acc0 = __builtin_amdgcn_mfma_f32_16x16x32_bf16(a[0][kf], b[kf], acc0, 0, 0, 0);
            acc1 = __builtin_amdgcn_mfma_f32_16x16x32_bf16(a[1][kf], b[kf], acc1, 0, 0, 0);
        }
        // D: col = lane&15, row = 4*(lane>>4)+r   [m89-verified]
        int ccol = ct * 16 + rf;
        if (ccol < NOUT) {
#pragma unroll
            for (int rt = 0; rt < 2; ++rt) {
                f32x4 acc = rt ? acc1 : acc0;
#pragma unroll
                for (int r = 0; r < 4; ++r) {
                    int row = row0 + rt * 16 + kg * 4 + r;
                    if (row < M) {
                        float v = acc[r];
                        if (base) v += base[(size_t)row * ldbase + ccol];
                        if (bias) v += bias[ccol];
                        if (OUTBF)
                            ((__hip_bfloat16*)C)[(size_t)row * ldc + ccol] = __float2bfloat16(v);
                        else
                            ((float*)C)[(size_t)row * ldc + ccol] = v;
                    }
                }
            }
        }
    }
}

// --------------------------- attention el / er ----------------------------
template<int H, int D>
__global__ __launch_bounds__(256) void k_eler(
    const __hip_bfloat16* __restrict__ ftb,
    const float* __restrict__ attn_l, const float* __restrict__ attn_r,
    const float* __restrict__ oi,
    float* __restrict__ el, float* __restrict__ er, int N) {
    constexpr int W = H * D;
    const int lane = threadIdx.x & 63;
    const int n = blockIdx.x * 4 + (threadIdx.x >> 6);
    if (n >= N) return;
    float pl[H], pr[H];
#pragma unroll
    for (int h = 0; h < H; ++h) { pl[h] = 0.f; pr[h] = 0.f; }
    for (int idx = lane; idx < W; idx += 64) {
        float f = __bfloat162float(ftb[(size_t)n * W + idx]);
        int h = idx / D;
        pl[h] += f * attn_l[idx];
        pr[h] += f * attn_r[idx];
    }
#pragma unroll
    for (int off = 32; off; off >>= 1)
#pragma unroll
        for (int h = 0; h < H; ++h) {
            pl[h] += __shfl_xor(pl[h], off);
            pr[h] += __shfl_xor(pr[h], off);
        }
    if (lane == 0) {
        float o = oi[n];
#pragma unroll
        for (int h = 0; h < H; ++h) {
            el[(size_t)n * H + h] = o * pl[h];
            er[(size_t)n * H + h] = pr[h];
        }
    }
}

// ------------- fused edge softmax + message aggregation (per dst) ---------
template<int H, int D>
__global__ __launch_bounds__(256) void k_agg(
    const __hip_bfloat16* __restrict__ ftb,
    const float* __restrict__ el, const float* __restrict__ er,
    const int* __restrict__ row_ptr, const int* __restrict__ csr_src,
    const float* __restrict__ oi, const float* __restrict__ insq,
    float* __restrict__ out, int ldc, int N) {
    constexpr int W = H * D;
    constexpr int J = (W + 63) / 64;
    const int lane = threadIdx.x & 63;
    const int v = blockIdx.x * 4 + (threadIdx.x >> 6);
    if (v >= N) return;
    const int s = row_ptr[v], e = row_ptr[v + 1];
    float erv[H], mh[H];
#pragma unroll
    for (int h = 0; h < H; ++h) { erv[h] = er[(size_t)v * H + h]; mh[h] = -3.0e38f; }
    for (int p = s; p < e; ++p) {
        int u = csr_src[p];
#pragma unroll
        for (int h = 0; h < H; ++h) {
            float sc = el[(size_t)u * H + h] + erv[h];
            sc = sc >= 0.f ? sc : 0.2f * sc;
            mh[h] = fmaxf(mh[h], sc);
        }
    }
    float denom[H], acc[J];
#pragma unroll
    for (int h = 0; h < H; ++h) denom[h] = 0.f;
#pragma unroll
    for (int j = 0; j < J; ++j) acc[j] = 0.f;
    for (int p = s; p < e; ++p) {
        int u = csr_src[p];
        float ou = oi[u];
        float wo[H];
#pragma unroll
        for (int h = 0; h < H; ++h) {
            float sc = el[(size_t)u * H + h] + erv[h];
            sc = sc >= 0.f ? sc : 0.2f * sc;
            float w = __expf(sc - mh[h]);
            denom[h] += w;
            wo[h] = w * ou;
        }
#pragma unroll
        for (int j = 0; j < J; ++j) {
            int idx = lane + j * 64;
            if (idx < W) {
                int h = idx / D;
                acc[j] += wo[h] * __bfloat162float(ftb[(size_t)u * W + idx]);
            }
        }
    }
    float iv = insq[v];
#pragma unroll
    for (int j = 0; j < J; ++j) {
        int idx = lane + j * 64;
        if (idx < W) {
            int h = idx / D;
            out[(size_t)v * ldc + idx] += iv * acc[j] / fmaxf(denom[h], 1e-9f);
        }
    }
}

// ------------------------------ batch norm --------------------------------
// Partial sums: grid-stride over rows, many blocks. psum[pr*F+col].
template<int F>
__global__ __launch_bounds__(256) void k_bn_part(const float* __restrict__ in, int ldin, int N,
                                                 float* __restrict__ psum, float* __restrict__ psum2) {
    constexpr int SL = 256 / F;              // rows per block per step
    const int col = threadIdx.x % F;
    const int pr = blockIdx.x * SL + threadIdx.x / F;
    const int PRT = gridDim.x * SL;
    float s = 0.f, s2 = 0.f;
    for (int r = pr; r < N; r += PRT) {
        float v = in[(size_t)r * ldin + col];
        s += v; s2 += v * v;
    }
    psum[(size_t)pr * F + col] = s;
    psum2[(size_t)pr * F + col] = s2;
}

// Finalize: one block per column, tree-reduce PRT partials.
template<int F>
__global__ __launch_bounds__(256) void k_bn_fin(const float* __restrict__ psum,
                                                const float* __restrict__ psum2, int PRT,
                                                const float* __restrict__ gamma,
                                                const float* __restrict__ beta,
                                                float* __restrict__ scale,
                                                float* __restrict__ shift, int N) {
    const int col = blockIdx.x;
    float s = 0.f, s2 = 0.f;
    for (int p = threadIdx.x; p < PRT; p += 256) {
        s += psum[(size_t)p * F + col];
        s2 += psum2[(size_t)p * F + col];
    }
#pragma unroll
    for (int off = 32; off; off >>= 1) {
        s += __shfl_down(s, off);
        s2 += __shfl_down(s2, off);
    }
    __shared__ float sm[4], sm2[4];
    const int wave = threadIdx.x >> 6, lane = threadIdx.x & 63;
    if (lane == 0) { sm[wave] = s; sm2[wave] = s2; }
    __syncthreads();
    if (threadIdx.x == 0) {
        s = sm[0] + sm[1] + sm[2] + sm[3];
        s2 = sm2[0] + sm2[1] + sm2[2] + sm2[3];
        float mu = s / N;
        float var = s2 / N - mu * mu;
        float isd = rsqrtf(var + 1e-5f);
        float g = gamma[col];
        scale[col] = g * isd;
        shift[col] = beta[col] - g * isd * mu;
    }
}

template<int F>
__global__ __launch_bounds__(256) void k_bn_apply(const float* __restrict__ in, int ldin, int N,
                                                  const float* __restrict__ scale,
                                                  const float* __restrict__ shift,
                                                  __hip_bfloat16* __restrict__ outbf) {
    int total = N * F;
    for (int idx = blockIdx.x * blockDim.x + threadIdx.x; idx < total;
         idx += gridDim.x * blockDim.x) {
        int r = idx / F, c = idx % F;
        float v = in[(size_t)r * ldin + c] * scale[c] + shift[c];
        outbf[idx] = __float2bfloat16(fmaxf(v, 0.f));
    }
}

// ------------------------------- launcher ---------------------------------
extern "C" void kernel_launch(void* const* d_in, const int* in_sizes, int n_in,
                              void* d_out, int out_size, void* d_ws, size_t ws_size,
                              hipStream_t stream) {
    const float* x           = (const float*)d_in[0];
    const int*   src         = (const int*)d_in[1];
    const int*   dst         = (const int*)d_in[2];
    const float* W0          = (const float*)d_in[3];
    const float* attn_l0     = (const float*)d_in[4];
    const float* attn_r0     = (const float*)d_in[5];
    const float* resW0       = (const float*)d_in[6];
    const float* mid_bn_g    = (const float*)d_in[7];
    const float* mid_bn_b    = (const float*)d_in[8];
    const float* mid_W       = (const float*)d_in[9];
    const float* mid_attn_l  = (const float*)d_in[10];
    const float* mid_attn_r  = (const float*)d_in[11];
    const float* mid_resW    = (const float*)d_in[12];
    const float* norm_gamma  = (const float*)d_in[13];
    const float* norm_beta   = (const float*)d_in[14];
    const float* W_last      = (const float*)d_in[15];
    const float* attn_l_last = (const float*)d_in[16];
    const float* attn_r_last = (const float*)d_in[17];
    const float* resW_last   = (const float*)d_in[18];
    const float* bias_last   = (const float*)d_in[19];

    const int N = in_sizes[0] / IN_F;
    const int E = in_sizes[1];

    // ---- workspace carve-up (256B aligned) ----
    char* p = (char*)d_ws;
    size_t used = 0;
    auto take = [&](size_t bytes) -> char* {
        char* r = p;
        size_t adv = (bytes + 255) & ~(size_t)255;
        p += adv; used += adv;
        return r;
    };
    float*          h       = (float*)take((size_t)N * HIDW * 4);
    __hip_bfloat16* xbf     = (__hip_bfloat16*)take((size_t)N * HIDW * 2);
    __hip_bfloat16* ftb     = (__hip_bfloat16*)take((size_t)N * HIDW * 2);
    float*          el      = (float*)take((size_t)N * 4 * 4);
    float*          er      = (float*)take((size_t)N * 4 * 4);
    float*          oi      = (float*)take((size_t)N * 4);
    float*          insq    = (float*)take((size_t)N * 4);
    int*            indeg   = (int*)take((size_t)N * 4);
    int*            outdeg  = (int*)take((size_t)N * 4);
    int*            row_ptr = (int*)take((size_t)(N + 1) * 4);
    int*            cursor  = (int*)take((size_t)N * 4);
    int*            csr_src = (int*)take((size_t)E * 4);
    int*            bsum    = (int*)take(256 * 4);
    float*          psum    = (float*)take(1 << 20);    // up to 2048 partial rows x 128 / 1024 x 256
    float*          psum2   = (float*)take(1 << 20);
    float*          scale   = (float*)take(1024);
    float*          shift   = (float*)take(1024);
    __hip_bfloat16* W0bf      = (__hip_bfloat16*)take(65536 * 2);
    __hip_bfloat16* resW0bf   = (__hip_bfloat16*)take(65536 * 2);
    __hip_bfloat16* midWbf    = (__hip_bfloat16*)take(65536 * 2);
    __hip_bfloat16* midresWbf = (__hip_bfloat16*)take(65536 * 2);
    __hip_bfloat16* Wlastbf   = (__hip_bfloat16*)take(10240 * 2);
    __hip_bfloat16* resWlastbf= (__hip_bfloat16*)take(10240 * 2);
    if (used > ws_size) return;   // out of workspace: leave output poisoned (visible failure)

    const int nbN = (N + 255) / 256;
    const int NB4 = (N + 3) / 4;
    const int GW  = (N + 127) / 128;
    const int BNB = 1024;                       // BN partial blocks

    // ---- graph prep ----
    hipMemsetAsync(indeg, 0, (size_t)N * 4, stream);
    hipMemsetAsync(outdeg, 0, (size_t)N * 4, stream);
    k_hist<<<1024, 256, 0, stream>>>(src, dst, E, outdeg, indeg);
    k_scan1<<<nbN, 256, 0, stream>>>(indeg, N, row_ptr + 1, bsum);
    k_scan2<<<1, 256, 0, stream>>>(bsum, nbN);
    k_scan3<<<nbN, 256, 0, stream>>>(row_ptr + 1, bsum, N);
    hipMemcpyAsync(cursor, row_ptr, (size_t)N * 4, hipMemcpyDeviceToDevice, stream);
    k_scatter<<<1024, 256, 0, stream>>>(src, dst, E, cursor, csr_src);
    k_deg<<<nbN, 256, 0, stream>>>(outdeg, indeg, oi, insq, N);

    // ---- weight + input conversion ----
    k_cvt6<<<dim3(64, 6), 256, 0, stream>>>(W0, W0bf, 65536,
                                            resW0, resW0bf, 65536,
                                            mid_W, midWbf, 65536,
                                            mid_resW, midresWbf, 65536,
                                            W_last, Wlastbf, 10240,
                                            resW_last, resWlastbf, 10240);
    k_cvt<<<2048, 256, 0, stream>>>(x, xbf, N * IN_F);

    // ---- layer 0: GATConv(256 -> 4x64) ----
    k_gemm_bt<256, 256, true><<<GW, 256, 0, stream>>>(xbf, W0bf, ftb, N, 256, nullptr, 0, nullptr);
    k_eler<4, 64><<<NB4, 256, 0, stream>>>(ftb, attn_l0, attn_r0, oi, el, er, N);
    k_gemm_bt<256, 256, false><<<GW, 256, 0, stream>>>(xbf, resW0bf, h, N, 256, nullptr, 0, nullptr);
    k_agg<4, 64><<<NB4, 256, 0, stream>>>(ftb, el, er, row_ptr, csr_src, oi, insq, h, 256, N);

    // ---- reversible middle layers ----
    for (int l = 0; l < 2; ++l) {
        for (int g = 0; g < 2; ++g) {
            const int inoff  = (g == 0) ? 128 : 0;
            const int outoff = (g == 0) ? 0 : 128;
            const int pg = l * 2 + g;
            k_bn_part<128><<<BNB, 256, 0, stream>>>(h + inoff, 256, N, psum, psum2);
            k_bn_fin<128><<<128, 256, 0, stream>>>(psum, psum2, BNB * 2,
                                                   mid_bn_g + pg * 128, mid_bn_b + pg * 128,
                                                   scale, shift, N);
            k_bn_apply<128><<<2048, 256, 0, stream>>>(h + inoff, 256, N, scale, shift, xbf);
            k_gemm_bt<128, 128, true><<<GW, 256, 0, stream>>>(xbf, midWbf + pg * 16384, ftb,
                                                              N, 128, nullptr, 0, nullptr);
            k_eler<4, 32><<<NB4, 256, 0, stream>>>(ftb, mid_attn_l + pg * 128,
                                                   mid_attn_r + pg * 128, oi, el, er, N);
            k_gemm_bt<128, 128, false><<<GW, 256, 0, stream>>>(xbf, midresWbf + pg * 16384,
                                                               h + outoff, N, 256,
                                                               h + outoff, 256, nullptr);
            k_agg<4, 32><<<NB4, 256, 0, stream>>>(ftb, el, er, row_ptr, csr_src, oi, insq,
                                                  h + outoff, 256, N);
        }
    }

    // ---- final norm + GATConv(256 -> 1x40) + bias ----
    k_bn_part<256><<<BNB, 256, 0, stream>>>(h, 256, N, psum, psum2);
    k_bn_fin<256><<<256, 256, 0, stream>>>(psum, psum2, BNB, norm_gamma, norm_beta, scale, shift, N);
    k_bn_apply<256><<<2048, 256, 0, stream>>>(h, 256, N, scale, shift, xbf);
    k_gemm_bt<256, 40, true><<<GW, 256, 0, stream>>>(xbf, Wlastbf, ftb, N, 40, nullptr, 0, nullptr);
    k_eler<1, 40><<<NB4, 256, 0, stream>>>(ftb, attn_l_last, attn_r_last, oi, el, er, N);
    k_gemm_bt<256, 40, false><<<GW, 256, 0, stream>>>(xbf, resWlastbf, (float*)d_out, N, 40,
                                                      nullptr, 0, bias_last);
    k_agg<1, 40><<<NB4, 256, 0, stream>>>(ftb, el, er, row_ptr, csr_src, oi, insq,
                                          (float*)d_out, 40, N);
}

// Round 3
// 856.904 us; speedup vs baseline: 2.1414x; 1.4028x over previous
//
#include <hip/hip_runtime.h>
#include <hip/hip_bf16.h>

// ---------------------------------------------------------------------------
// RevGAT forward on MI355X.
//   degrees -> CSR(dst) -> bf16 weight/x conversion ->
//   [GATconv x5 with bf16 MFMA GEMMs + fused edge-softmax aggregation]
//   with BN(+relu)->bf16 between layers.
// R2: BN stats widened to 1024 blocks (950us -> ~60us).
// R3: k_agg single-pass (softmax shift-invariance), per-lane contiguous
//     vectorized gather, 1 exp/edge/lane, unroll-2 edge loop.
// ---------------------------------------------------------------------------

#define IN_F   256
#define HIDW   256          // HEADS*HID
#define CLS    40

typedef __attribute__((ext_vector_type(8))) __bf16 bf16x8;
typedef __attribute__((ext_vector_type(4))) float  f32x4;

__device__ inline bf16x8 zb8() {
    bf16x8 v;
#pragma unroll
    for (int i = 0; i < 8; ++i) v[i] = (__bf16)0.f;
    return v;
}
__device__ inline bf16x8 ldb8(const __hip_bfloat16* p) {
    return *reinterpret_cast<const bf16x8*>(p);
}
__device__ inline float bf2f(unsigned short u) {
    union { unsigned int i; float f; } c;
    c.i = ((unsigned int)u) << 16;
    return c.f;
}

// ------------------------------ graph prep --------------------------------
__global__ void k_hist(const int* __restrict__ src, const int* __restrict__ dst,
                       int E, int* __restrict__ outdeg, int* __restrict__ indeg) {
    for (int e = blockIdx.x * blockDim.x + threadIdx.x; e < E; e += gridDim.x * blockDim.x) {
        atomicAdd(&outdeg[src[e]], 1);
        atomicAdd(&indeg[dst[e]], 1);
    }
}

__global__ void k_scan1(const int* __restrict__ cnt, int N, int* __restrict__ rp1,
                        int* __restrict__ bsum) {
    __shared__ int sm[256];
    int i = blockIdx.x * 256 + threadIdx.x;
    int v = (i < N) ? cnt[i] : 0;
    sm[threadIdx.x] = v;
    __syncthreads();
    for (int off = 1; off < 256; off <<= 1) {
        int t = (threadIdx.x >= off) ? sm[threadIdx.x - off] : 0;
        __syncthreads();
        sm[threadIdx.x] += t;
        __syncthreads();
    }
    if (i < N) rp1[i] = sm[threadIdx.x];                  // inclusive within block
    if (threadIdx.x == 255) bsum[blockIdx.x] = sm[255];
}

__global__ void k_scan2(int* __restrict__ bsum, int nb) {
    __shared__ int sm[256];
    int v = (threadIdx.x < nb) ? bsum[threadIdx.x] : 0;
    sm[threadIdx.x] = v;
    __syncthreads();
    for (int off = 1; off < 256; off <<= 1) {
        int t = (threadIdx.x >= off) ? sm[threadIdx.x - off] : 0;
        __syncthreads();
        sm[threadIdx.x] += t;
        __syncthreads();
    }
    if (threadIdx.x < nb) bsum[threadIdx.x] = sm[threadIdx.x] - v;   // exclusive
}

__global__ void k_scan3(int* __restrict__ rp1, const int* __restrict__ bsumExcl, int N) {
    int i = blockIdx.x * 256 + threadIdx.x;
    if (i < N) rp1[i] += bsumExcl[blockIdx.x];
    if (blockIdx.x == 0 && threadIdx.x == 0) rp1[-1] = 0;            // row_ptr[0] = 0
}

__global__ void k_scatter(const int* __restrict__ src, const int* __restrict__ dst,
                          int E, int* __restrict__ cursor, int* __restrict__ csr_src) {
    for (int e = blockIdx.x * blockDim.x + threadIdx.x; e < E; e += gridDim.x * blockDim.x) {
        int d = dst[e];
        int pos = atomicAdd(&cursor[d], 1);
        csr_src[pos] = src[e];
    }
}

__global__ void k_deg(const int* __restrict__ outdeg, const int* __restrict__ indeg,
                      float* __restrict__ oi, float* __restrict__ insq, int N) {
    int i = blockIdx.x * 256 + threadIdx.x;
    if (i < N) {
        int od = outdeg[i]; if (od < 1) od = 1;
        int id = indeg[i];  if (id < 1) id = 1;
        oi[i]   = rsqrtf((float)od);
        insq[i] = sqrtf((float)id);
    }
}

// --------------------------- dtype conversion -----------------------------
__global__ void k_cvt(const float* __restrict__ s, __hip_bfloat16* __restrict__ d, int n) {
    for (int i = blockIdx.x * blockDim.x + threadIdx.x; i < n; i += gridDim.x * blockDim.x)
        d[i] = __float2bfloat16(s[i]);
}

__global__ void k_cvt6(const float* s0, __hip_bfloat16* d0, int n0,
                       const float* s1, __hip_bfloat16* d1, int n1,
                       const float* s2, __hip_bfloat16* d2, int n2,
                       const float* s3, __hip_bfloat16* d3, int n3,
                       const float* s4, __hip_bfloat16* d4, int n4,
                       const float* s5, __hip_bfloat16* d5, int n5) {
    const float* ss; __hip_bfloat16* dd; int nn;
    switch (blockIdx.y) {
        case 0: ss = s0; dd = d0; nn = n0; break;
        case 1: ss = s1; dd = d1; nn = n1; break;
        case 2: ss = s2; dd = d2; nn = n2; break;
        case 3: ss = s3; dd = d3; nn = n3; break;
        case 4: ss = s4; dd = d4; nn = n4; break;
        default: ss = s5; dd = d5; nn = n5; break;
    }
    for (int i = blockIdx.x * blockDim.x + threadIdx.x; i < nn; i += gridDim.x * blockDim.x)
        dd[i] = __float2bfloat16(ss[i]);
}

// ------------------------------ bf16 GEMM ---------------------------------
// C[M,NOUT] = A[M,K] @ B[NOUT,K]^T  (+ base) (+ bias), A/B bf16, acc f32.
template<int K, int NOUT, bool OUTBF>
__global__ __launch_bounds__(256) void k_gemm_bt(
    const __hip_bfloat16* __restrict__ A,
    const __hip_bfloat16* __restrict__ B,
    void* __restrict__ C, int M, int ldc,
    const float* __restrict__ base, int ldbase,
    const float* __restrict__ bias) {
    constexpr int KF  = K / 32;
    constexpr int NCT = (NOUT + 15) / 16;
    const int wave = threadIdx.x >> 6, lane = threadIdx.x & 63;
    const int row0 = blockIdx.x * 128 + wave * 32;
    const int rf = lane & 15, kg = lane >> 4;

    bf16x8 a[2][KF];
#pragma unroll
    for (int rt = 0; rt < 2; ++rt) {
        int row = row0 + rt * 16 + rf;
        const __hip_bfloat16* ap = A + (size_t)row * K + kg * 8;
#pragma unroll
        for (int kf = 0; kf < KF; ++kf)
            a[rt][kf] = (row < M) ? ldb8(ap + kf * 32) : zb8();
    }

    for (int ct = 0; ct < NCT; ++ct) {
        int col = ct * 16 + rf;
        bf16x8 b[KF];
        const __hip_bfloat16* bp = B + (size_t)col * K + kg * 8;
#pragma unroll
        for (int kf = 0; kf < KF; ++kf)
            b[kf] = (col < NOUT) ? ldb8(bp + kf * 32) : zb8();
        f32x4 acc0 = {0.f, 0.f, 0.f, 0.f};
        f32x4 acc1 = {0.f, 0.f, 0.f, 0.f};
#pragma unroll
        for (int kf = 0; kf < KF; ++kf) {
            acc0 = __builtin_amdgcn_mfma_f32_16x16x32_bf16(a[0][kf], b[kf], acc0, 0, 0, 0);
            acc1 = __builtin_amdgcn_mfma_f32_16x16x32_bf16(a[1][kf], b[kf], acc1, 0, 0, 0);
        }
        // D: col = lane&15, row = 4*(lane>>4)+r   [m89-verified]
        int ccol = ct * 16 + rf;
        if (ccol < NOUT) {
#pragma unroll
            for (int rt = 0; rt < 2; ++rt) {
                f32x4 acc = rt ? acc1 : acc0;
#pragma unroll
                for (int r = 0; r < 4; ++r) {
                    int row = row0 + rt * 16 + kg * 4 + r;
                    if (row < M) {
                        float v = acc[r];
                        if (base) v += base[(size_t)row * ldbase + ccol];
                        if (bias) v += bias[ccol];
                        if (OUTBF)
                            ((__hip_bfloat16*)C)[(size_t)row * ldc + ccol] = __float2bfloat16(v);
                        else
                            ((float*)C)[(size_t)row * ldc + ccol] = v;
                    }
                }
            }
        }
    }
}

// --------------------------- attention el / er ----------------------------
template<int H, int D>
__global__ __launch_bounds__(256) void k_eler(
    const __hip_bfloat16* __restrict__ ftb,
    const float* __restrict__ attn_l, const float* __restrict__ attn_r,
    const float* __restrict__ oi,
    float* __restrict__ el, float* __restrict__ er, int N) {
    constexpr int W = H * D;
    const int lane = threadIdx.x & 63;
    const int n = blockIdx.x * 4 + (threadIdx.x >> 6);
    if (n >= N) return;
    float pl[H], pr[H];
#pragma unroll
    for (int h = 0; h < H; ++h) { pl[h] = 0.f; pr[h] = 0.f; }
    for (int idx = lane; idx < W; idx += 64) {
        float f = __bfloat162float(ftb[(size_t)n * W + idx]);
        int h = idx / D;
        pl[h] += f * attn_l[idx];
        pr[h] += f * attn_r[idx];
    }
#pragma unroll
    for (int off = 32; off; off >>= 1)
#pragma unroll
        for (int h = 0; h < H; ++h) {
            pl[h] += __shfl_xor(pl[h], off);
            pr[h] += __shfl_xor(pr[h], off);
        }
    if (lane == 0) {
        float o = oi[n];
#pragma unroll
        for (int h = 0; h < H; ++h) {
            el[(size_t)n * H + h] = o * pl[h];
            er[(size_t)n * H + h] = pr[h];
        }
    }
}

// ------------- fused edge softmax + message aggregation (per dst) ---------
// Single pass: softmax is shift-invariant, so exp(sc)/sum(exp(sc)) ==
// exp(sc-max)/sum(exp(sc-max)) exactly; scores are O(1) here (clamp +-30 is
// a never-triggering overflow guard). Lane l owns EPL contiguous columns,
// all within one head -> 1 exp per edge per lane, one vector gather.
template<int H, int D>
__global__ __launch_bounds__(256) void k_agg(
    const __hip_bfloat16* __restrict__ ftb,
    const float* __restrict__ el, const float* __restrict__ er,
    const int* __restrict__ row_ptr, const int* __restrict__ csr_src,
    const float* __restrict__ oi, const float* __restrict__ insq,
    float* __restrict__ out, int ldc, int N) {
    constexpr int W = H * D;
    constexpr int EPL = (W >= 64) ? (W / 64) : 1;   // elements per lane
    const int lane = threadIdx.x & 63;
    const int v = blockIdx.x * 4 + (threadIdx.x >> 6);
    if (v >= N) return;
    const bool act = (W >= 64) || (lane < W);
    const int col0 = lane * EPL;
    const int myh = (W >= 64) ? (col0 / D) : 0;
    const int s = row_ptr[v], e = row_ptr[v + 1];
    if (!act) return;
    const float erv = er[(size_t)v * H + myh];

    float denom = 0.f;
    float acc[EPL];
#pragma unroll
    for (int k = 0; k < EPL; ++k) acc[k] = 0.f;

    auto edge = [&](int u) {
        float sc = el[(size_t)u * H + myh] + erv;
        sc = sc >= 0.f ? sc : 0.2f * sc;
        sc = fminf(fmaxf(sc, -30.f), 30.f);
        float w = __expf(sc);
        denom += w;
        float wo = w * oi[u];
        const __hip_bfloat16* fp = ftb + (size_t)u * W + col0;
        if constexpr (EPL == 4) {
            ushort4 q = *reinterpret_cast<const ushort4*>(fp);
            acc[0] += wo * bf2f(q.x); acc[1] += wo * bf2f(q.y);
            acc[2] += wo * bf2f(q.z); acc[3] += wo * bf2f(q.w);
        } else if constexpr (EPL == 2) {
            ushort2 q = *reinterpret_cast<const ushort2*>(fp);
            acc[0] += wo * bf2f(q.x); acc[1] += wo * bf2f(q.y);
        } else {
            acc[0] += wo * bf2f(*reinterpret_cast<const unsigned short*>(fp));
        }
    };

    int p = s;
    for (; p + 1 < e; p += 2) {          // unroll-2: two independent gathers in flight
        int ua = csr_src[p], ub = csr_src[p + 1];
        edge(ua);
        edge(ub);
    }
    if (p < e) edge(csr_src[p]);

    float iv = insq[v] / fmaxf(denom, 1e-9f);
    float* op = out + (size_t)v * ldc + col0;
    if constexpr (EPL == 4) {
        float4 o = *reinterpret_cast<float4*>(op);
        o.x += iv * acc[0]; o.y += iv * acc[1]; o.z += iv * acc[2]; o.w += iv * acc[3];
        *reinterpret_cast<float4*>(op) = o;
    } else if constexpr (EPL == 2) {
        float2 o = *reinterpret_cast<float2*>(op);
        o.x += iv * acc[0]; o.y += iv * acc[1];
        *reinterpret_cast<float2*>(op) = o;
    } else {
        op[0] += iv * acc[0];
    }
}

// ------------------------------ batch norm --------------------------------
template<int F>
__global__ __launch_bounds__(256) void k_bn_part(const float* __restrict__ in, int ldin, int N,
                                                 float* __restrict__ psum, float* __restrict__ psum2) {
    constexpr int SL = 256 / F;              // rows per block per step
    const int col = threadIdx.x % F;
    const int pr = blockIdx.x * SL + threadIdx.x / F;
    const int PRT = gridDim.x * SL;
    float s = 0.f, s2 = 0.f;
    for (int r = pr; r < N; r += PRT) {
        float v = in[(size_t)r * ldin + col];
        s += v; s2 += v * v;
    }
    psum[(size_t)pr * F + col] = s;
    psum2[(size_t)pr * F + col] = s2;
}

template<int F>
__global__ __launch_bounds__(256) void k_bn_fin(const float* __restrict__ psum,
                                                const float* __restrict__ psum2, int PRT,
                                                const float* __restrict__ gamma,
                                                const float* __restrict__ beta,
                                                float* __restrict__ scale,
                                                float* __restrict__ shift, int N) {
    const int col = blockIdx.x;
    float s = 0.f, s2 = 0.f;
    for (int p = threadIdx.x; p < PRT; p += 256) {
        s += psum[(size_t)p * F + col];
        s2 += psum2[(size_t)p * F + col];
    }
#pragma unroll
    for (int off = 32; off; off >>= 1) {
        s += __shfl_down(s, off);
        s2 += __shfl_down(s2, off);
    }
    __shared__ float sm[4], sm2[4];
    const int wave = threadIdx.x >> 6, lane = threadIdx.x & 63;
    if (lane == 0) { sm[wave] = s; sm2[wave] = s2; }
    __syncthreads();
    if (threadIdx.x == 0) {
        s = sm[0] + sm[1] + sm[2] + sm[3];
        s2 = sm2[0] + sm2[1] + sm2[2] + sm2[3];
        float mu = s / N;
        float var = s2 / N - mu * mu;
        float isd = rsqrtf(var + 1e-5f);
        float g = gamma[col];
        scale[col] = g * isd;
        shift[col] = beta[col] - g * isd * mu;
    }
}

template<int F>
__global__ __launch_bounds__(256) void k_bn_apply(const float* __restrict__ in, int ldin, int N,
                                                  const float* __restrict__ scale,
                                                  const float* __restrict__ shift,
                                                  __hip_bfloat16* __restrict__ outbf) {
    int total = N * F;
    for (int idx = blockIdx.x * blockDim.x + threadIdx.x; idx < total;
         idx += gridDim.x * blockDim.x) {
        int r = idx / F, c = idx % F;
        float v = in[(size_t)r * ldin + c] * scale[c] + shift[c];
        outbf[idx] = __float2bfloat16(fmaxf(v, 0.f));
    }
}

// ------------------------------- launcher ---------------------------------
extern "C" void kernel_launch(void* const* d_in, const int* in_sizes, int n_in,
                              void* d_out, int out_size, void* d_ws, size_t ws_size,
                              hipStream_t stream) {
    const float* x           = (const float*)d_in[0];
    const int*   src         = (const int*)d_in[1];
    const int*   dst         = (const int*)d_in[2];
    const float* W0          = (const float*)d_in[3];
    const float* attn_l0     = (const float*)d_in[4];
    const float* attn_r0     = (const float*)d_in[5];
    const float* resW0       = (const float*)d_in[6];
    const float* mid_bn_g    = (const float*)d_in[7];
    const float* mid_bn_b    = (const float*)d_in[8];
    const float* mid_W       = (const float*)d_in[9];
    const float* mid_attn_l  = (const float*)d_in[10];
    const float* mid_attn_r  = (const float*)d_in[11];
    const float* mid_resW    = (const float*)d_in[12];
    const float* norm_gamma  = (const float*)d_in[13];
    const float* norm_beta   = (const float*)d_in[14];
    const float* W_last      = (const float*)d_in[15];
    const float* attn_l_last = (const float*)d_in[16];
    const float* attn_r_last = (const float*)d_in[17];
    const float* resW_last   = (const float*)d_in[18];
    const float* bias_last   = (const float*)d_in[19];

    const int N = in_sizes[0] / IN_F;
    const int E = in_sizes[1];

    // ---- workspace carve-up (256B aligned) ----
    char* p = (char*)d_ws;
    size_t used = 0;
    auto take = [&](size_t bytes) -> char* {
        char* r = p;
        size_t adv = (bytes + 255) & ~(size_t)255;
        p += adv; used += adv;
        return r;
    };
    float*          h       = (float*)take((size_t)N * HIDW * 4);
    __hip_bfloat16* xbf     = (__hip_bfloat16*)take((size_t)N * HIDW * 2);
    __hip_bfloat16* ftb     = (__hip_bfloat16*)take((size_t)N * HIDW * 2);
    float*          el      = (float*)take((size_t)N * 4 * 4);
    float*          er      = (float*)take((size_t)N * 4 * 4);
    float*          oi      = (float*)take((size_t)N * 4);
    float*          insq    = (float*)take((size_t)N * 4);
    int*            indeg   = (int*)take((size_t)N * 4);
    int*            outdeg  = (int*)take((size_t)N * 4);
    int*            row_ptr = (int*)take((size_t)(N + 1) * 4);
    int*            cursor  = (int*)take((size_t)N * 4);
    int*            csr_src = (int*)take((size_t)E * 4);
    int*            bsum    = (int*)take(256 * 4);
    float*          psum    = (float*)take(1 << 20);
    float*          psum2   = (float*)take(1 << 20);
    float*          scale   = (float*)take(1024);
    float*          shift   = (float*)take(1024);
    __hip_bfloat16* W0bf      = (__hip_bfloat16*)take(65536 * 2);
    __hip_bfloat16* resW0bf   = (__hip_bfloat16*)take(65536 * 2);
    __hip_bfloat16* midWbf    = (__hip_bfloat16*)take(65536 * 2);
    __hip_bfloat16* midresWbf = (__hip_bfloat16*)take(65536 * 2);
    __hip_bfloat16* Wlastbf   = (__hip_bfloat16*)take(10240 * 2);
    __hip_bfloat16* resWlastbf= (__hip_bfloat16*)take(10240 * 2);
    if (used > ws_size) return;   // out of workspace: leave output poisoned (visible failure)

    const int nbN = (N + 255) / 256;
    const int NB4 = (N + 3) / 4;
    const int GW  = (N + 127) / 128;
    const int BNB = 1024;                       // BN partial blocks

    // ---- graph prep ----
    hipMemsetAsync(indeg, 0, (size_t)N * 4, stream);
    hipMemsetAsync(outdeg, 0, (size_t)N * 4, stream);
    k_hist<<<1024, 256, 0, stream>>>(src, dst, E, outdeg, indeg);
    k_scan1<<<nbN, 256, 0, stream>>>(indeg, N, row_ptr + 1, bsum);
    k_scan2<<<1, 256, 0, stream>>>(bsum, nbN);
    k_scan3<<<nbN, 256, 0, stream>>>(row_ptr + 1, bsum, N);
    hipMemcpyAsync(cursor, row_ptr, (size_t)N * 4, hipMemcpyDeviceToDevice, stream);
    k_scatter<<<1024, 256, 0, stream>>>(src, dst, E, cursor, csr_src);
    k_deg<<<nbN, 256, 0, stream>>>(outdeg, indeg, oi, insq, N);

    // ---- weight + input conversion ----
    k_cvt6<<<dim3(64, 6), 256, 0, stream>>>(W0, W0bf, 65536,
                                            resW0, resW0bf, 65536,
                                            mid_W, midWbf, 65536,
                                            mid_resW, midresWbf, 65536,
                                            W_last, Wlastbf, 10240,
                                            resW_last, resWlastbf, 10240);
    k_cvt<<<2048, 256, 0, stream>>>(x, xbf, N * IN_F);

    // ---- layer 0: GATConv(256 -> 4x64) ----
    k_gemm_bt<256, 256, true><<<GW, 256, 0, stream>>>(xbf, W0bf, ftb, N, 256, nullptr, 0, nullptr);
    k_eler<4, 64><<<NB4, 256, 0, stream>>>(ftb, attn_l0, attn_r0, oi, el, er, N);
    k_gemm_bt<256, 256, false><<<GW, 256, 0, stream>>>(xbf, resW0bf, h, N, 256, nullptr, 0, nullptr);
    k_agg<4, 64><<<NB4, 256, 0, stream>>>(ftb, el, er, row_ptr, csr_src, oi, insq, h, 256, N);

    // ---- reversible middle layers ----
    for (int l = 0; l < 2; ++l) {
        for (int g = 0; g < 2; ++g) {
            const int inoff  = (g == 0) ? 128 : 0;
            const int outoff = (g == 0) ? 0 : 128;
            const int pg = l * 2 + g;
            k_bn_part<128><<<BNB, 256, 0, stream>>>(h + inoff, 256, N, psum, psum2);
            k_bn_fin<128><<<128, 256, 0, stream>>>(psum, psum2, BNB * 2,
                                                   mid_bn_g + pg * 128, mid_bn_b + pg * 128,
                                                   scale, shift, N);
            k_bn_apply<128><<<2048, 256, 0, stream>>>(h + inoff, 256, N, scale, shift, xbf);
            k_gemm_bt<128, 128, true><<<GW, 256, 0, stream>>>(xbf, midWbf + pg * 16384, ftb,
                                                              N, 128, nullptr, 0, nullptr);
            k_eler<4, 32><<<NB4, 256, 0, stream>>>(ftb, mid_attn_l + pg * 128,
                                                   mid_attn_r + pg * 128, oi, el, er, N);
            k_gemm_bt<128, 128, false><<<GW, 256, 0, stream>>>(xbf, midresWbf + pg * 16384,
                                                               h + outoff, N, 256,
                                                               h + outoff, 256, nullptr);
            k_agg<4, 32><<<NB4, 256, 0, stream>>>(ftb, el, er, row_ptr, csr_src, oi, insq,
                                                  h + outoff, 256, N);
        }
    }

    // ---- final norm + GATConv(256 -> 1x40) + bias ----
    k_bn_part<256><<<BNB, 256, 0, stream>>>(h, 256, N, psum, psum2);
    k_bn_fin<256><<<256, 256, 0, stream>>>(psum, psum2, BNB, norm_gamma, norm_beta, scale, shift, N);
    k_bn_apply<256><<<2048, 256, 0, stream>>>(h, 256, N, scale, shift, xbf);
    k_gemm_bt<256, 40, true><<<GW, 256, 0, stream>>>(xbf, Wlastbf, ftb, N, 40, nullptr, 0, nullptr);
    k_eler<1, 40><<<NB4, 256, 0, stream>>>(ftb, attn_l_last, attn_r_last, oi, el, er, N);
    k_gemm_bt<256, 40, false><<<GW, 256, 0, stream>>>(xbf, resWlastbf, (float*)d_out, N, 40,
                                                      nullptr, 0, bias_last);
    k_agg<1, 40><<<NB4, 256, 0, stream>>>(ftb, el, er, row_ptr, csr_src, oi, insq,
                                          (float*)d_out, 40, N);
}

// Round 4
// 705.736 us; speedup vs baseline: 2.6000x; 1.2142x over previous
//
#include <hip/hip_runtime.h>
#include <hip/hip_bf16.h>

// ---------------------------------------------------------------------------
// RevGAT forward on MI355X.
//   degrees -> CSR(dst) -> bf16 weight conversion ->
//   [GATconv x5: fused (BN+cvt)->MFMA GEMM->(el/er epilogue) + fused
//    single-pass edge-softmax aggregation] ; BN stats separate.
// R2: BN stats widened (950us -> ~60us).
// R3: k_agg single-pass, vectorized per-lane gather (110 -> 49us).
// R4: k_agg unroll-4 MLP; el/er fused into GEMM epilogue (drops k_eler x6);
//     BN-apply + f32->bf16 fused into GEMM A-load (drops k_bn_apply x5, k_cvt).
// ---------------------------------------------------------------------------

#define IN_F   256
#define HIDW   256          // HEADS*HID
#define CLS    40

typedef __attribute__((ext_vector_type(8))) __bf16 bf16x8;
typedef __attribute__((ext_vector_type(4))) float  f32x4;

__device__ inline bf16x8 zb8() {
    bf16x8 v;
#pragma unroll
    for (int i = 0; i < 8; ++i) v[i] = (__bf16)0.f;
    return v;
}
__device__ inline bf16x8 ldb8(const __hip_bfloat16* p) {
    return *reinterpret_cast<const bf16x8*>(p);
}
__device__ inline float bf2f(unsigned short u) {
    union { unsigned int i; float f; } c;
    c.i = ((unsigned int)u) << 16;
    return c.f;
}

// ------------------------------ graph prep --------------------------------
__global__ void k_hist(const int* __restrict__ src, const int* __restrict__ dst,
                       int E, int* __restrict__ outdeg, int* __restrict__ indeg) {
    for (int e = blockIdx.x * blockDim.x + threadIdx.x; e < E; e += gridDim.x * blockDim.x) {
        atomicAdd(&outdeg[src[e]], 1);
        atomicAdd(&indeg[dst[e]], 1);
    }
}

__global__ void k_scan1(const int* __restrict__ cnt, int N, int* __restrict__ rp1,
                        int* __restrict__ bsum) {
    __shared__ int sm[256];
    int i = blockIdx.x * 256 + threadIdx.x;
    int v = (i < N) ? cnt[i] : 0;
    sm[threadIdx.x] = v;
    __syncthreads();
    for (int off = 1; off < 256; off <<= 1) {
        int t = (threadIdx.x >= off) ? sm[threadIdx.x - off] : 0;
        __syncthreads();
        sm[threadIdx.x] += t;
        __syncthreads();
    }
    if (i < N) rp1[i] = sm[threadIdx.x];                  // inclusive within block
    if (threadIdx.x == 255) bsum[blockIdx.x] = sm[255];
}

__global__ void k_scan2(int* __restrict__ bsum, int nb) {
    __shared__ int sm[256];
    int v = (threadIdx.x < nb) ? bsum[threadIdx.x] : 0;
    sm[threadIdx.x] = v;
    __syncthreads();
    for (int off = 1; off < 256; off <<= 1) {
        int t = (threadIdx.x >= off) ? sm[threadIdx.x - off] : 0;
        __syncthreads();
        sm[threadIdx.x] += t;
        __syncthreads();
    }
    if (threadIdx.x < nb) bsum[threadIdx.x] = sm[threadIdx.x] - v;   // exclusive
}

__global__ void k_scan3(int* __restrict__ rp1, const int* __restrict__ bsumExcl, int N) {
    int i = blockIdx.x * 256 + threadIdx.x;
    if (i < N) rp1[i] += bsumExcl[blockIdx.x];
    if (blockIdx.x == 0 && threadIdx.x == 0) rp1[-1] = 0;            // row_ptr[0] = 0
}

__global__ void k_scatter(const int* __restrict__ src, const int* __restrict__ dst,
                          int E, int* __restrict__ cursor, int* __restrict__ csr_src) {
    for (int e = blockIdx.x * blockDim.x + threadIdx.x; e < E; e += gridDim.x * blockDim.x) {
        int d = dst[e];
        int pos = atomicAdd(&cursor[d], 1);
        csr_src[pos] = src[e];
    }
}

__global__ void k_deg(const int* __restrict__ outdeg, const int* __restrict__ indeg,
                      float* __restrict__ oi, float* __restrict__ insq, int N) {
    int i = blockIdx.x * 256 + threadIdx.x;
    if (i < N) {
        int od = outdeg[i]; if (od < 1) od = 1;
        int id = indeg[i];  if (id < 1) id = 1;
        oi[i]   = rsqrtf((float)od);
        insq[i] = sqrtf((float)id);
    }
}

// --------------------------- weight conversion ----------------------------
__global__ void k_cvt6(const float* s0, __hip_bfloat16* d0, int n0,
                       const float* s1, __hip_bfloat16* d1, int n1,
                       const float* s2, __hip_bfloat16* d2, int n2,
                       const float* s3, __hip_bfloat16* d3, int n3,
                       const float* s4, __hip_bfloat16* d4, int n4,
                       const float* s5, __hip_bfloat16* d5, int n5) {
    const float* ss; __hip_bfloat16* dd; int nn;
    switch (blockIdx.y) {
        case 0: ss = s0; dd = d0; nn = n0; break;
        case 1: ss = s1; dd = d1; nn = n1; break;
        case 2: ss = s2; dd = d2; nn = n2; break;
        case 3: ss = s3; dd = d3; nn = n3; break;
        case 4: ss = s4; dd = d4; nn = n4; break;
        default: ss = s5; dd = d5; nn = n5; break;
    }
    for (int i = blockIdx.x * blockDim.x + threadIdx.x; i < nn; i += gridDim.x * blockDim.x)
        dd[i] = __float2bfloat16(ss[i]);
}

// ------------------------------ fused GEMM --------------------------------
// C[M,NOUT] = act(A) @ B[NOUT,K]^T (+base) (+bias)
//   act(A): f32 A, optional per-col BN (relu(scale*a+shift)) then bf16 round.
//   ELER: epilogue computes el[row,h] = oi[row]*sum_d ft0*attn_l,
//         er[row,h] = sum_d ft0*attn_r   (H heads, head-contiguous ct tiles).
// Wave: 32 rows x NOUT cols; C/D frag: col=lane&15, row=4*(lane>>4)+r.
template<int K, int NOUT, int H, bool OUTBF, bool ELER, bool BN>
__global__ __launch_bounds__(256) void k_gemm_bt(
    const float* __restrict__ A, int lda,
    const __hip_bfloat16* __restrict__ B,
    void* __restrict__ C, int M, int ldc,
    const float* __restrict__ scale, const float* __restrict__ shift,
    const float* __restrict__ base, int ldbase,
    const float* __restrict__ bias,
    const float* __restrict__ attn_l, const float* __restrict__ attn_r,
    const float* __restrict__ oi,
    float* __restrict__ el, float* __restrict__ er) {
    constexpr int KF  = K / 32;
    constexpr int NCT = (NOUT + 15) / 16;
    constexpr int HG  = ELER ? H : 1;        // head groups for epilogue flush
    constexpr int CTH = NCT / HG;            // ct tiles per head group
    static_assert(NCT % HG == 0, "head tiling");
    const int wave = threadIdx.x >> 6, lane = threadIdx.x & 63;
    const int row0 = blockIdx.x * 128 + wave * 32;
    const int rf = lane & 15, kg = lane >> 4;

    // ---- A fragments: f32 load + optional BN + bf16 round ----
    bf16x8 a[2][KF];
#pragma unroll
    for (int kf = 0; kf < KF; ++kf) {
        const int c0 = kg * 8 + kf * 32;
        float sc[8], sh[8];
        if (BN) {
            float4 s01 = *reinterpret_cast<const float4*>(scale + c0);
            float4 s23 = *reinterpret_cast<const float4*>(scale + c0 + 4);
            float4 h01 = *reinterpret_cast<const float4*>(shift + c0);
            float4 h23 = *reinterpret_cast<const float4*>(shift + c0 + 4);
            sc[0]=s01.x; sc[1]=s01.y; sc[2]=s01.z; sc[3]=s01.w;
            sc[4]=s23.x; sc[5]=s23.y; sc[6]=s23.z; sc[7]=s23.w;
            sh[0]=h01.x; sh[1]=h01.y; sh[2]=h01.z; sh[3]=h01.w;
            sh[4]=h23.x; sh[5]=h23.y; sh[6]=h23.z; sh[7]=h23.w;
        }
#pragma unroll
        for (int rt = 0; rt < 2; ++rt) {
            const int row = row0 + rt * 16 + rf;
            if (row < M) {
                const float* ap = A + (size_t)row * lda + c0;
                float4 f0 = *reinterpret_cast<const float4*>(ap);
                float4 f1 = *reinterpret_cast<const float4*>(ap + 4);
                float v[8] = {f0.x, f0.y, f0.z, f0.w, f1.x, f1.y, f1.z, f1.w};
                bf16x8 t;
#pragma unroll
                for (int i = 0; i < 8; ++i) {
                    float u = v[i];
                    if (BN) u = fmaxf(u * sc[i] + sh[i], 0.f);
                    t[i] = (__bf16)u;
                }
                a[rt][kf] = t;
            } else {
                a[rt][kf] = zb8();
            }
        }
    }

    int ct = 0;
    for (int hh = 0; hh < HG; ++hh) {
        float elp[2][4], erp[2][4];
        if (ELER) {
#pragma unroll
            for (int rt = 0; rt < 2; ++rt)
#pragma unroll
                for (int r = 0; r < 4; ++r) { elp[rt][r] = 0.f; erp[rt][r] = 0.f; }
        }
        for (int cth = 0; cth < CTH; ++cth, ++ct) {
            const int ccol = ct * 16 + rf;
            bf16x8 b[KF];
            const __hip_bfloat16* bp = B + (size_t)ccol * K + kg * 8;
#pragma unroll
            for (int kf = 0; kf < KF; ++kf)
                b[kf] = (ccol < NOUT) ? ldb8(bp + kf * 32) : zb8();
            f32x4 acc0 = {0.f, 0.f, 0.f, 0.f};
            f32x4 acc1 = {0.f, 0.f, 0.f, 0.f};
#pragma unroll
            for (int kf = 0; kf < KF; ++kf) {
                acc0 = __builtin_amdgcn_mfma_f32_16x16x32_bf16(a[0][kf], b[kf], acc0, 0, 0, 0);
                acc1 = __builtin_amdgcn_mfma_f32_16x16x32_bf16(a[1][kf], b[kf], acc1, 0, 0, 0);
            }
            float al = 0.f, ar = 0.f;
            if (ELER && ccol < NOUT) { al = attn_l[ccol]; ar = attn_r[ccol]; }
            if (ccol < NOUT) {
#pragma unroll
                for (int rt = 0; rt < 2; ++rt) {
                    f32x4 acc = rt ? acc1 : acc0;
#pragma unroll
                    for (int r = 0; r < 4; ++r) {
                        float v = acc[r];
                        if (ELER) { elp[rt][r] += v * al; erp[rt][r] += v * ar; }
                        const int row = row0 + rt * 16 + kg * 4 + r;
                        if (row < M) {
                            if (base) v += base[(size_t)row * ldbase + ccol];
                            if (bias) v += bias[ccol];
                            if (OUTBF)
                                ((__hip_bfloat16*)C)[(size_t)row * ldc + ccol] = __float2bfloat16(v);
                            else
                                ((float*)C)[(size_t)row * ldc + ccol] = v;
                        }
                    }
                }
            }
        }
        if (ELER) {
            // reduce over the 16 rf-lanes (same kg) -> full row dot
#pragma unroll
            for (int off = 1; off <= 8; off <<= 1)
#pragma unroll
                for (int rt = 0; rt < 2; ++rt)
#pragma unroll
                    for (int r = 0; r < 4; ++r) {
                        elp[rt][r] += __shfl_xor(elp[rt][r], off);
                        erp[rt][r] += __shfl_xor(erp[rt][r], off);
                    }
            if (rf == 0) {
#pragma unroll
                for (int rt = 0; rt < 2; ++rt)
#pragma unroll
                    for (int r = 0; r < 4; ++r) {
                        const int row = row0 + rt * 16 + kg * 4 + r;
                        if (row < M) {
                            el[(size_t)row * H + hh] = oi[row] * elp[rt][r];
                            er[(size_t)row * H + hh] = erp[rt][r];
                        }
                    }
            }
        }
    }
}

// ------------- fused edge softmax + message aggregation (per dst) ---------
// Single pass (softmax shift-invariance; clamp +-30 is a never-triggering
// overflow guard). Lane owns EPL contiguous cols within one head.
// R4: unroll-4 with hoisted loads for memory-level parallelism.
template<int EPL>
__device__ inline void ldrow(const __hip_bfloat16* fp, float* f) {
    if constexpr (EPL == 4) {
        ushort4 q = *reinterpret_cast<const ushort4*>(fp);
        f[0] = bf2f(q.x); f[1] = bf2f(q.y); f[2] = bf2f(q.z); f[3] = bf2f(q.w);
    } else if constexpr (EPL == 2) {
        ushort2 q = *reinterpret_cast<const ushort2*>(fp);
        f[0] = bf2f(q.x); f[1] = bf2f(q.y);
    } else {
        f[0] = bf2f(*reinterpret_cast<const unsigned short*>(fp));
    }
}
__device__ inline float escore(float sc) {
    sc = sc >= 0.f ? sc : 0.2f * sc;
    sc = fminf(fmaxf(sc, -30.f), 30.f);
    return __expf(sc);
}

template<int H, int D>
__global__ __launch_bounds__(256) void k_agg(
    const __hip_bfloat16* __restrict__ ftb,
    const float* __restrict__ el, const float* __restrict__ er,
    const int* __restrict__ row_ptr, const int* __restrict__ csr_src,
    const float* __restrict__ oi, const float* __restrict__ insq,
    float* __restrict__ out, int ldc, int N) {
    constexpr int W = H * D;
    constexpr int EPL = (W >= 64) ? (W / 64) : 1;
    const int lane = threadIdx.x & 63;
    const int v = blockIdx.x * 4 + (threadIdx.x >> 6);
    if (v >= N) return;
    if (W < 64 && lane >= W) return;
    const int col0 = lane * EPL;
    const int myh = (W >= 64) ? (col0 / D) : 0;
    const int s = row_ptr[v], e = row_ptr[v + 1];
    const float erv = er[(size_t)v * H + myh];

    float denom = 0.f;
    float acc[EPL];
#pragma unroll
    for (int k = 0; k < EPL; ++k) acc[k] = 0.f;

    int p = s;
    for (; p + 3 < e; p += 4) {
        const int u0 = csr_src[p + 0], u1 = csr_src[p + 1];
        const int u2 = csr_src[p + 2], u3 = csr_src[p + 3];
        float f0[EPL], f1[EPL], f2[EPL], f3[EPL];
        ldrow<EPL>(ftb + (size_t)u0 * W + col0, f0);
        ldrow<EPL>(ftb + (size_t)u1 * W + col0, f1);
        ldrow<EPL>(ftb + (size_t)u2 * W + col0, f2);
        ldrow<EPL>(ftb + (size_t)u3 * W + col0, f3);
        const float s0 = el[(size_t)u0 * H + myh], s1 = el[(size_t)u1 * H + myh];
        const float s2 = el[(size_t)u2 * H + myh], s3 = el[(size_t)u3 * H + myh];
        const float o0 = oi[u0], o1 = oi[u1], o2 = oi[u2], o3 = oi[u3];
        const float w0 = escore(s0 + erv), w1 = escore(s1 + erv);
        const float w2 = escore(s2 + erv), w3 = escore(s3 + erv);
        denom += (w0 + w1) + (w2 + w3);
        const float a0 = w0 * o0, a1 = w1 * o1, a2 = w2 * o2, a3 = w3 * o3;
#pragma unroll
        for (int k = 0; k < EPL; ++k)
            acc[k] += a0 * f0[k] + a1 * f1[k] + a2 * f2[k] + a3 * f3[k];
    }
    for (; p < e; ++p) {
        const int u = csr_src[p];
        float f[EPL];
        ldrow<EPL>(ftb + (size_t)u * W + col0, f);
        const float w = escore(el[(size_t)u * H + myh] + erv);
        denom += w;
        const float a = w * oi[u];
#pragma unroll
        for (int k = 0; k < EPL; ++k) acc[k] += a * f[k];
    }

    const float iv = insq[v] / fmaxf(denom, 1e-9f);
    float* op = out + (size_t)v * ldc + col0;
    if constexpr (EPL == 4) {
        float4 o = *reinterpret_cast<float4*>(op);
        o.x += iv * acc[0]; o.y += iv * acc[1]; o.z += iv * acc[2]; o.w += iv * acc[3];
        *reinterpret_cast<float4*>(op) = o;
    } else if constexpr (EPL == 2) {
        float2 o = *reinterpret_cast<float2*>(op);
        o.x += iv * acc[0]; o.y += iv * acc[1];
        *reinterpret_cast<float2*>(op) = o;
    } else {
        op[0] += iv * acc[0];
    }
}

// ------------------------------ batch norm --------------------------------
template<int F>
__global__ __launch_bounds__(256) void k_bn_part(const float* __restrict__ in, int ldin, int N,
                                                 float* __restrict__ psum, float* __restrict__ psum2) {
    constexpr int SL = 256 / F;
    const int col = threadIdx.x % F;
    const int pr = blockIdx.x * SL + threadIdx.x / F;
    const int PRT = gridDim.x * SL;
    float s = 0.f, s2 = 0.f;
    for (int r = pr; r < N; r += PRT) {
        float v = in[(size_t)r * ldin + col];
        s += v; s2 += v * v;
    }
    psum[(size_t)pr * F + col] = s;
    psum2[(size_t)pr * F + col] = s2;
}

template<int F>
__global__ __launch_bounds__(256) void k_bn_fin(const float* __restrict__ psum,
                                                const float* __restrict__ psum2, int PRT,
                                                const float* __restrict__ gamma,
                                                const float* __restrict__ beta,
                                                float* __restrict__ scale,
                                                float* __restrict__ shift, int N) {
    const int col = blockIdx.x;
    float s = 0.f, s2 = 0.f;
    for (int p = threadIdx.x; p < PRT; p += 256) {
        s += psum[(size_t)p * F + col];
        s2 += psum2[(size_t)p * F + col];
    }
#pragma unroll
    for (int off = 32; off; off >>= 1) {
        s += __shfl_down(s, off);
        s2 += __shfl_down(s2, off);
    }
    __shared__ float sm[4], sm2[4];
    const int wave = threadIdx.x >> 6, lane = threadIdx.x & 63;
    if (lane == 0) { sm[wave] = s; sm2[wave] = s2; }
    __syncthreads();
    if (threadIdx.x == 0) {
        s = sm[0] + sm[1] + sm[2] + sm[3];
        s2 = sm2[0] + sm2[1] + sm2[2] + sm2[3];
        float mu = s / N;
        float var = s2 / N - mu * mu;
        float isd = rsqrtf(var + 1e-5f);
        float g = gamma[col];
        scale[col] = g * isd;
        shift[col] = beta[col] - g * isd * mu;
    }
}

// ------------------------------- launcher ---------------------------------
extern "C" void kernel_launch(void* const* d_in, const int* in_sizes, int n_in,
                              void* d_out, int out_size, void* d_ws, size_t ws_size,
                              hipStream_t stream) {
    const float* x           = (const float*)d_in[0];
    const int*   src         = (const int*)d_in[1];
    const int*   dst         = (const int*)d_in[2];
    const float* W0          = (const float*)d_in[3];
    const float* attn_l0     = (const float*)d_in[4];
    const float* attn_r0     = (const float*)d_in[5];
    const float* resW0       = (const float*)d_in[6];
    const float* mid_bn_g    = (const float*)d_in[7];
    const float* mid_bn_b    = (const float*)d_in[8];
    const float* mid_W       = (const float*)d_in[9];
    const float* mid_attn_l  = (const float*)d_in[10];
    const float* mid_attn_r  = (const float*)d_in[11];
    const float* mid_resW    = (const float*)d_in[12];
    const float* norm_gamma  = (const float*)d_in[13];
    const float* norm_beta   = (const float*)d_in[14];
    const float* W_last      = (const float*)d_in[15];
    const float* attn_l_last = (const float*)d_in[16];
    const float* attn_r_last = (const float*)d_in[17];
    const float* resW_last   = (const float*)d_in[18];
    const float* bias_last   = (const float*)d_in[19];

    const int N = in_sizes[0] / IN_F;
    const int E = in_sizes[1];

    // ---- workspace carve-up (256B aligned) ----
    char* p = (char*)d_ws;
    size_t used = 0;
    auto take = [&](size_t bytes) -> char* {
        char* r = p;
        size_t adv = (bytes + 255) & ~(size_t)255;
        p += adv; used += adv;
        return r;
    };
    float*          h       = (float*)take((size_t)N * HIDW * 4);
    __hip_bfloat16* ftb     = (__hip_bfloat16*)take((size_t)N * HIDW * 2);
    float*          el      = (float*)take((size_t)N * 4 * 4);
    float*          er      = (float*)take((size_t)N * 4 * 4);
    float*          oi      = (float*)take((size_t)N * 4);
    float*          insq    = (float*)take((size_t)N * 4);
    int*            indeg   = (int*)take((size_t)N * 4);
    int*            outdeg  = (int*)take((size_t)N * 4);
    int*            row_ptr = (int*)take((size_t)(N + 1) * 4);
    int*            cursor  = (int*)take((size_t)N * 4);
    int*            csr_src = (int*)take((size_t)E * 4);
    int*            bsum    = (int*)take(256 * 4);
    float*          psum    = (float*)take(1 << 20);
    float*          psum2   = (float*)take(1 << 20);
    float*          scale   = (float*)take(1024);
    float*          shift   = (float*)take(1024);
    __hip_bfloat16* W0bf      = (__hip_bfloat16*)take(65536 * 2);
    __hip_bfloat16* resW0bf   = (__hip_bfloat16*)take(65536 * 2);
    __hip_bfloat16* midWbf    = (__hip_bfloat16*)take(65536 * 2);
    __hip_bfloat16* midresWbf = (__hip_bfloat16*)take(65536 * 2);
    __hip_bfloat16* Wlastbf   = (__hip_bfloat16*)take(10240 * 2);
    __hip_bfloat16* resWlastbf= (__hip_bfloat16*)take(10240 * 2);
    if (used > ws_size) return;   // out of workspace: leave output poisoned (visible failure)

    const int nbN = (N + 255) / 256;
    const int NB4 = (N + 3) / 4;
    const int GW  = (N + 127) / 128;
    const int BNB = 1024;

    // ---- graph prep ----
    hipMemsetAsync(indeg, 0, (size_t)N * 4, stream);
    hipMemsetAsync(outdeg, 0, (size_t)N * 4, stream);
    k_hist<<<1024, 256, 0, stream>>>(src, dst, E, outdeg, indeg);
    k_scan1<<<nbN, 256, 0, stream>>>(indeg, N, row_ptr + 1, bsum);
    k_scan2<<<1, 256, 0, stream>>>(bsum, nbN);
    k_scan3<<<nbN, 256, 0, stream>>>(row_ptr + 1, bsum, N);
    hipMemcpyAsync(cursor, row_ptr, (size_t)N * 4, hipMemcpyDeviceToDevice, stream);
    k_scatter<<<1024, 256, 0, stream>>>(src, dst, E, cursor, csr_src);
    k_deg<<<nbN, 256, 0, stream>>>(outdeg, indeg, oi, insq, N);

    // ---- weight conversion ----
    k_cvt6<<<dim3(64, 6), 256, 0, stream>>>(W0, W0bf, 65536,
                                            resW0, resW0bf, 65536,
                                            mid_W, midWbf, 65536,
                                            mid_resW, midresWbf, 65536,
                                            W_last, Wlastbf, 10240,
                                            resW_last, resWlastbf, 10240);

    // ---- layer 0: GATConv(256 -> 4x64), A = x (f32, no BN) ----
    k_gemm_bt<256, 256, 4, true, true, false><<<GW, 256, 0, stream>>>(
        x, 256, W0bf, ftb, N, 256, nullptr, nullptr, nullptr, 0, nullptr,
        attn_l0, attn_r0, oi, el, er);
    k_gemm_bt<256, 256, 1, false, false, false><<<GW, 256, 0, stream>>>(
        x, 256, resW0bf, h, N, 256, nullptr, nullptr, nullptr, 0, nullptr,
        nullptr, nullptr, nullptr, nullptr, nullptr);
    k_agg<4, 64><<<NB4, 256, 0, stream>>>(ftb, el, er, row_ptr, csr_src, oi, insq, h, 256, N);

    // ---- reversible middle layers ----
    for (int l = 0; l < 2; ++l) {
        for (int g = 0; g < 2; ++g) {
            const int inoff  = (g == 0) ? 128 : 0;
            const int outoff = (g == 0) ? 0 : 128;
            const int pg = l * 2 + g;
            k_bn_part<128><<<BNB, 256, 0, stream>>>(h + inoff, 256, N, psum, psum2);
            k_bn_fin<128><<<128, 256, 0, stream>>>(psum, psum2, BNB * 2,
                                                   mid_bn_g + pg * 128, mid_bn_b + pg * 128,
                                                   scale, shift, N);
            k_gemm_bt<128, 128, 4, true, true, true><<<GW, 256, 0, stream>>>(
                h + inoff, 256, midWbf + pg * 16384, ftb, N, 128, scale, shift,
                nullptr, 0, nullptr, mid_attn_l + pg * 128, mid_attn_r + pg * 128, oi, el, er);
            k_gemm_bt<128, 128, 1, false, false, true><<<GW, 256, 0, stream>>>(
                h + inoff, 256, midresWbf + pg * 16384, h + outoff, N, 256, scale, shift,
                h + outoff, 256, nullptr, nullptr, nullptr, nullptr, nullptr, nullptr);
            k_agg<4, 32><<<NB4, 256, 0, stream>>>(ftb, el, er, row_ptr, csr_src, oi, insq,
                                                  h + outoff, 256, N);
        }
    }

    // ---- final norm + GATConv(256 -> 1x40) + bias ----
    k_bn_part<256><<<BNB, 256, 0, stream>>>(h, 256, N, psum, psum2);
    k_bn_fin<256><<<256, 256, 0, stream>>>(psum, psum2, BNB, norm_gamma, norm_beta, scale, shift, N);
    k_gemm_bt<256, 40, 1, true, true, true><<<GW, 256, 0, stream>>>(
        h, 256, Wlastbf, ftb, N, 40, scale, shift, nullptr, 0, nullptr,
        attn_l_last, attn_r_last, oi, el, er);
    k_gemm_bt<256, 40, 1, false, false, true><<<GW, 256, 0, stream>>>(
        h, 256, resWlastbf, (float*)d_out, N, 40, scale, shift, nullptr, 0, bias_last,
        nullptr, nullptr, nullptr, nullptr, nullptr);
    k_agg<1, 40><<<NB4, 256, 0, stream>>>(ftb, el, er, row_ptr, csr_src, oi, insq,
                                          (float*)d_out, 40, N);
}